// Round 8
// baseline (826.160 us; speedup 1.0000x reference)
//
#include <hip/hip_runtime.h>
#include <math.h>

#define NF 128       // feature width (both in and out of every layer)
#define NPART 8      // one partition per XCD (blockIdx % 8 -> XCD, round-robin)
#define SCAN_CHUNK 1024

typedef int      vint4   __attribute__((ext_vector_type(4)));
typedef float    vfloat4 __attribute__((ext_vector_type(4)));
typedef _Float16 vhalf4  __attribute__((ext_vector_type(4)));

// ---------------------------------------------------------------------------
// XCD-partitioned degree count: partition p owns node range [lo,hi).
// Edge-list reads are NONTEMPORAL: the stream is touched once per pass and
// must not evict the cnt slice from the XCD's L2 (round-7 lesson: streaming
// allocations evicted dirty destination lines -> full write amplification).
// ---------------------------------------------------------------------------
__global__ __launch_bounds__(256) void k_count(const int* __restrict__ col,
                                               int* __restrict__ cnt, int E, int N) {
  int part = blockIdx.x & (NPART - 1);
  int lo = (int)((long)part * N / NPART);
  int hi = (int)((long)(part + 1) * N / NPART);
  int bip = blockIdx.x >> 3;          // block index within partition
  int nbp = gridDim.x >> 3;           // blocks per partition
  int stride = nbp * 256;
  int t = bip * 256 + threadIdx.x;

  const vint4* c4 = reinterpret_cast<const vint4*>(col);
  int E4 = E >> 2;
  for (int i = t; i < E4; i += stride) {
    vint4 c = __builtin_nontemporal_load(&c4[i]);
    if (c.x >= lo && c.x < hi) atomicAdd(&cnt[c.x], 1);
    if (c.y >= lo && c.y < hi) atomicAdd(&cnt[c.y], 1);
    if (c.z >= lo && c.z < hi) atomicAdd(&cnt[c.z], 1);
    if (c.w >= lo && c.w < hi) atomicAdd(&cnt[c.w], 1);
  }
  // tail (E not multiple of 4)
  for (int i = (E4 << 2) + t; i < E; i += stride) {
    int c = col[i];
    if (c >= lo && c < hi) atomicAdd(&cnt[c], 1);
  }
}

// ---------------------------------------------------------------------------
// Ordered exclusive prefix-sum of cnt -> offs (so each partition's csr slice
// is contiguous and stays in its own L2). 3 tiny kernels over 400 KB.
// k_scanB requires nChunks <= 128 (N <= 131072).
// ---------------------------------------------------------------------------
__global__ __launch_bounds__(256) void k_scanA(const int* __restrict__ cnt,
                                               int* __restrict__ chunkTot, int N) {
  int c0 = blockIdx.x * SCAN_CHUNK + threadIdx.x * 4;
  int s = 0;
#pragma unroll
  for (int j = 0; j < 4; ++j) {
    int idx = c0 + j;
    if (idx < N) s += cnt[idx];
  }
  __shared__ int red[256];
  red[threadIdx.x] = s;
  __syncthreads();
  for (int o = 128; o > 0; o >>= 1) {
    if (threadIdx.x < o) red[threadIdx.x] += red[threadIdx.x + o];
    __syncthreads();
  }
  if (threadIdx.x == 0) chunkTot[blockIdx.x] = red[0];
}

__global__ __launch_bounds__(128) void k_scanB(const int* __restrict__ chunkTot,
                                               int* __restrict__ chunkOff, int nChunks) {
  __shared__ int buf[128];
  int t = threadIdx.x;
  int v = (t < nChunks) ? chunkTot[t] : 0;
  buf[t] = v;
  __syncthreads();
  for (int o = 1; o < 128; o <<= 1) {
    int x = buf[t];
    if (t >= o) x += buf[t - o];
    __syncthreads();
    buf[t] = x;
    __syncthreads();
  }
  if (t < nChunks) chunkOff[t] = buf[t] - v;   // exclusive
}

__global__ __launch_bounds__(256) void k_scanC(const int* __restrict__ cnt,
                                               const int* __restrict__ chunkOff,
                                               int* __restrict__ offs,
                                               int* __restrict__ cursor,
                                               float* __restrict__ dinv, int N) {
  int t = threadIdx.x;
  int c0 = blockIdx.x * SCAN_CHUNK + t * 4;
  int v[4];
  int s = 0;
#pragma unroll
  for (int j = 0; j < 4; ++j) {
    int idx = c0 + j;
    v[j] = (idx < N) ? cnt[idx] : 0;
    s += v[j];
  }
  __shared__ int buf[256];
  buf[t] = s;
  __syncthreads();
  for (int o = 1; o < 256; o <<= 1) {
    int x = buf[t];
    if (t >= o) x += buf[t - o];
    __syncthreads();
    buf[t] = x;
    __syncthreads();
  }
  int excl = buf[t] - s + chunkOff[blockIdx.x];
#pragma unroll
  for (int j = 0; j < 4; ++j) {
    int idx = c0 + j;
    if (idx < N) {
      offs[idx] = excl;
      cursor[idx] = excl;
      dinv[idx] = rsqrtf((float)v[j] + 2.0f);   // deg + FILL(2.0) self-loop
      excl += v[j];
    }
  }
}

// ---------------------------------------------------------------------------
// XCD-partitioned CSR fill. Partition p writes only csr[offs[lo]..offs[hi])
// -- a contiguous ~1.6 MB slice that fits its L2. Edge-list reads are
// NONTEMPORAL so the stream cannot evict the slice; csr lines then fill
// completely in L2 and write back once.
// CSR stores ONLY the src index (weight folded into GEMM epilogue).
// ---------------------------------------------------------------------------
__global__ __launch_bounds__(256) void k_fill(const int* __restrict__ row,
                                              const int* __restrict__ col,
                                              int* __restrict__ cursor,
                                              int* __restrict__ csr, int E, int N) {
  int part = blockIdx.x & (NPART - 1);
  int lo = (int)((long)part * N / NPART);
  int hi = (int)((long)(part + 1) * N / NPART);
  int bip = blockIdx.x >> 3;
  int nbp = gridDim.x >> 3;
  int stride = nbp * 256;
  int t = bip * 256 + threadIdx.x;

  const vint4* c4 = reinterpret_cast<const vint4*>(col);
  const vint4* r4 = reinterpret_cast<const vint4*>(row);
  int E4 = E >> 2;
  for (int i = t; i < E4; i += stride) {
    vint4 c = __builtin_nontemporal_load(&c4[i]);
    vint4 r = __builtin_nontemporal_load(&r4[i]);
    if (c.x >= lo && c.x < hi) csr[atomicAdd(&cursor[c.x], 1)] = r.x;
    if (c.y >= lo && c.y < hi) csr[atomicAdd(&cursor[c.y], 1)] = r.y;
    if (c.z >= lo && c.z < hi) csr[atomicAdd(&cursor[c.z], 1)] = r.z;
    if (c.w >= lo && c.w < hi) csr[atomicAdd(&cursor[c.w], 1)] = r.w;
  }
  for (int i = (E4 << 2) + t; i < E; i += stride) {
    int c = col[i];
    if (c >= lo && c < hi) csr[atomicAdd(&cursor[c], 1)] = row[i];
  }
}

// ---------------------------------------------------------------------------
// GEMM: out[N,128] = dinv[row] * (H[N,128] @ W[128,128])  (f32 FMA, fp16 out)
// Tile 64 rows x 128 cols per block, BK=32 K-chunks.
// 256 threads; thread = 8 rows x 4 cols.
// ---------------------------------------------------------------------------
#define BM 64
#define BK 32
__global__ __launch_bounds__(256) void k_gemm(const float* __restrict__ H,
                                              const float* __restrict__ W,
                                              const float* __restrict__ dinv,
                                              _Float16* __restrict__ out, int nRows) {
  __shared__ float Wl[BK][NF];       // 16 KB
  __shared__ float Hl[BM][BK + 4];   // stride 36 floats (144 B, 16B-aligned), 9 KB

  const int tid = threadIdx.x;
  const int c4 = (tid & 31) * 4;     // output col base
  const int rg = (tid >> 5) * 8;     // row-group base (8 rows per thread)
  const int rowBase = blockIdx.x * BM;

  float acc[8][4];
#pragma unroll
  for (int j = 0; j < 8; ++j)
#pragma unroll
    for (int c = 0; c < 4; ++c) acc[j][c] = 0.f;

  for (int kc = 0; kc < NF; kc += BK) {
    __syncthreads();   // protect LDS from previous chunk's readers
    // stage W chunk [BK][128] (contiguous copy)
    {
      const float4* src = reinterpret_cast<const float4*>(W + (size_t)kc * NF);
      float4* dst = reinterpret_cast<float4*>(&Wl[0][0]);
      for (int i = tid; i < BK * NF / 4; i += 256) dst[i] = src[i];
    }
    // stage H chunk [BM][BK]
    {
      int r0 = tid >> 3;
      int cs = (tid & 7) * 4;
#pragma unroll
      for (int half = 0; half < 2; ++half) {
        int r = r0 + half * 32;
        int gr = rowBase + r;
        float4 v = make_float4(0.f, 0.f, 0.f, 0.f);
        if (gr < nRows)
          v = *reinterpret_cast<const float4*>(H + (size_t)gr * NF + kc + cs);
        *reinterpret_cast<float4*>(&Hl[r][cs]) = v;
      }
    }
    __syncthreads();

#pragma unroll
    for (int k = 0; k < BK; k += 4) {
      float4 w0 = *reinterpret_cast<float4*>(&Wl[k + 0][c4]);
      float4 w1 = *reinterpret_cast<float4*>(&Wl[k + 1][c4]);
      float4 w2 = *reinterpret_cast<float4*>(&Wl[k + 2][c4]);
      float4 w3 = *reinterpret_cast<float4*>(&Wl[k + 3][c4]);
#pragma unroll
      for (int j = 0; j < 8; ++j) {
        float4 hv = *reinterpret_cast<float4*>(&Hl[rg + j][k]);   // broadcast read
        acc[j][0] = fmaf(hv.x, w0.x, acc[j][0]);
        acc[j][1] = fmaf(hv.x, w0.y, acc[j][1]);
        acc[j][2] = fmaf(hv.x, w0.z, acc[j][2]);
        acc[j][3] = fmaf(hv.x, w0.w, acc[j][3]);
        acc[j][0] = fmaf(hv.y, w1.x, acc[j][0]);
        acc[j][1] = fmaf(hv.y, w1.y, acc[j][1]);
        acc[j][2] = fmaf(hv.y, w1.z, acc[j][2]);
        acc[j][3] = fmaf(hv.y, w1.w, acc[j][3]);
        acc[j][0] = fmaf(hv.z, w2.x, acc[j][0]);
        acc[j][1] = fmaf(hv.z, w2.y, acc[j][1]);
        acc[j][2] = fmaf(hv.z, w2.z, acc[j][2]);
        acc[j][3] = fmaf(hv.z, w2.w, acc[j][3]);
        acc[j][0] = fmaf(hv.w, w3.x, acc[j][0]);
        acc[j][1] = fmaf(hv.w, w3.y, acc[j][1]);
        acc[j][2] = fmaf(hv.w, w3.z, acc[j][2]);
        acc[j][3] = fmaf(hv.w, w3.w, acc[j][3]);
      }
    }
  }

#pragma unroll
  for (int j = 0; j < 8; ++j) {
    int gr = rowBase + rg + j;
    if (gr < nRows) {
      float dv = dinv[gr];
      vhalf4 v;
      v.x = (_Float16)(dv * acc[j][0]);
      v.y = (_Float16)(dv * acc[j][1]);
      v.z = (_Float16)(dv * acc[j][2]);
      v.w = (_Float16)(dv * acc[j][3]);
      *reinterpret_cast<vhalf4*>(out + (size_t)gr * NF + c4) = v;
    }
  }
}

// ---------------------------------------------------------------------------
// Aggregation: h[v] = tanh( dinv[v]*( sum_src tmp'[src] + 2*tmp'[v] ) + b )
// tmp' is fp16, pre-scaled by dinv (see k_gemm). f32 accumulation.
// Half-wave (32 lanes) per node, half4 (8 B) per lane = 256 B/row per instr.
// Edge loop unrolled x8, CSR read as 4-edge int4 nontemporal.
// ---------------------------------------------------------------------------
__device__ __forceinline__ float4 h2f(vhalf4 v) {
  return make_float4((float)v.x, (float)v.y, (float)v.z, (float)v.w);
}
__device__ __forceinline__ float4 add4(float4 a, float4 acc) {
  acc.x += a.x; acc.y += a.y; acc.z += a.z; acc.w += a.w;
  return acc;
}

__global__ __launch_bounds__(256) void k_agg(const _Float16* __restrict__ tmp,
                                             const int* __restrict__ offs,
                                             const int* __restrict__ ends,
                                             const int* __restrict__ csr,
                                             const float* __restrict__ dinv,
                                             const float* __restrict__ bias,
                                             float* __restrict__ hout, int N) {
  int node = (blockIdx.x * 256 + threadIdx.x) >> 5;
  if (node >= N) return;
  int lane = threadIdx.x & 31;

  float dv = dinv[node];

  const vhalf4* t4 = reinterpret_cast<const vhalf4*>(tmp);
  float4 hv = h2f(t4[(size_t)node * 32 + lane]);
  float4 acc = make_float4(2.f * hv.x, 2.f * hv.y, 2.f * hv.z, 2.f * hv.w);

  int s = offs[node], e = ends[node];
  int i = s;

  // align i to 4 so vint4 (4-edge) loads are 16B-aligned
  for (; (i & 3) && i < e; ++i) {
    float4 a = h2f(t4[(size_t)csr[i] * 32 + lane]);
    acc = add4(a, acc);
  }

  const vint4* cp = reinterpret_cast<const vint4*>(csr);
  for (; i + 8 <= e; i += 8) {
    vint4 p0 = __builtin_nontemporal_load(&cp[(i >> 2) + 0]);
    vint4 p1 = __builtin_nontemporal_load(&cp[(i >> 2) + 1]);
    float4 a0 = h2f(t4[(size_t)p0.x * 32 + lane]);
    float4 a1 = h2f(t4[(size_t)p0.y * 32 + lane]);
    float4 a2 = h2f(t4[(size_t)p0.z * 32 + lane]);
    float4 a3 = h2f(t4[(size_t)p0.w * 32 + lane]);
    float4 a4 = h2f(t4[(size_t)p1.x * 32 + lane]);
    float4 a5 = h2f(t4[(size_t)p1.y * 32 + lane]);
    float4 a6 = h2f(t4[(size_t)p1.z * 32 + lane]);
    float4 a7 = h2f(t4[(size_t)p1.w * 32 + lane]);
    acc = add4(a0, acc); acc = add4(a1, acc);
    acc = add4(a2, acc); acc = add4(a3, acc);
    acc = add4(a4, acc); acc = add4(a5, acc);
    acc = add4(a6, acc); acc = add4(a7, acc);
  }
  for (; i + 4 <= e; i += 4) {
    vint4 p = __builtin_nontemporal_load(&cp[i >> 2]);
    float4 a0 = h2f(t4[(size_t)p.x * 32 + lane]);
    float4 a1 = h2f(t4[(size_t)p.y * 32 + lane]);
    float4 a2 = h2f(t4[(size_t)p.z * 32 + lane]);
    float4 a3 = h2f(t4[(size_t)p.w * 32 + lane]);
    acc = add4(a0, acc); acc = add4(a1, acc);
    acc = add4(a2, acc); acc = add4(a3, acc);
  }
  for (; i < e; ++i) {
    float4 a = h2f(t4[(size_t)csr[i] * 32 + lane]);
    acc = add4(a, acc);
  }

  float4 b4 = reinterpret_cast<const float4*>(bias)[lane];
  vfloat4 r;
  r.x = tanhf(fmaf(dv, acc.x, b4.x));
  r.y = tanhf(fmaf(dv, acc.y, b4.y));
  r.z = tanhf(fmaf(dv, acc.z, b4.z));
  r.w = tanhf(fmaf(dv, acc.w, b4.w));
  vfloat4* outp = reinterpret_cast<vfloat4*>(hout) + ((size_t)node * 32 + lane);
  __builtin_nontemporal_store(r, outp);
}

// ---------------------------------------------------------------------------
// Pool (segment max + mean over sorted batch_index) fused with the linear head.
// One block (512 threads = 4 row-stripes of 128 features) per graph.
// ---------------------------------------------------------------------------
__global__ __launch_bounds__(512) void k_pool(const float* __restrict__ h,
                                              const int* __restrict__ batch,
                                              const float* __restrict__ Wout,
                                              const float* __restrict__ bout,
                                              float* __restrict__ out, int N) {
  int g = blockIdx.x;

  // lower_bound(batch, g) and lower_bound(batch, g+1): all threads redundantly
  int lo = 0, hi = N;
  while (lo < hi) { int mid = (lo + hi) >> 1; if (batch[mid] < g) lo = mid + 1; else hi = mid; }
  int s = lo;
  int lo2 = s, hi2 = N;
  while (lo2 < hi2) { int mid = (lo2 + hi2) >> 1; if (batch[mid] < g + 1) lo2 = mid + 1; else hi2 = mid; }
  int e = lo2;

  int f = threadIdx.x & 127;
  int stripe = threadIdx.x >> 7;   // 0..3

  float mx = -INFINITY, sm = 0.f;
  for (int n = s + stripe; n < e; n += 4) {
    float v = h[(size_t)n * NF + f];
    mx = fmaxf(mx, v);
    sm += v;
  }

  __shared__ float smx[4][NF];
  __shared__ float ssm[4][NF];
  smx[stripe][f] = mx;
  ssm[stripe][f] = sm;
  __syncthreads();

  if (stripe == 0) {
    mx = fmaxf(fmaxf(smx[0][f], smx[1][f]), fmaxf(smx[2][f], smx[3][f]));
    sm = ssm[0][f] + ssm[1][f] + ssm[2][f] + ssm[3][f];

    int cnt = e - s;
    float mean = sm / fmaxf((float)cnt, 1.0f);
    if (cnt == 0) mx = 0.f;

    float part = mx * Wout[f] + mean * Wout[NF + f];

    // reduce 128 threads = 2 waves
    for (int o = 32; o > 0; o >>= 1) part += __shfl_down(part, o);
    __shared__ float wsum[2];
    if ((threadIdx.x & 63) == 0) wsum[threadIdx.x >> 6] = part;
    __syncthreads();
    if (threadIdx.x == 0) out[g] = wsum[0] + wsum[1] + bout[0];
  }
}

// ---------------------------------------------------------------------------
// Driver
// ---------------------------------------------------------------------------
extern "C" void kernel_launch(void* const* d_in, const int* in_sizes, int n_in,
                              void* d_out, int out_size, void* d_ws, size_t ws_size,
                              hipStream_t stream) {
  const float* x     = (const float*)d_in[0];
  const int*   eidx  = (const int*)d_in[1];     // [2][E]
  const int*   batch = (const int*)d_in[2];     // [N]
  const float* W0    = (const float*)d_in[3];
  const float* b0    = (const float*)d_in[4];
  const float* Whid  = (const float*)d_in[5];   // [2][128][128]
  const float* bhid  = (const float*)d_in[6];   // [2][128]
  const float* Wout  = (const float*)d_in[7];   // [256]
  const float* bout  = (const float*)d_in[8];   // [1]
  float* out = (float*)d_out;

  const int N = in_sizes[0] / NF;
  const int E = in_sizes[1] / 2;
  const int G = out_size;

  const int* erow = eidx;
  const int* ecol = eidx + E;

  // workspace layout (256B aligned)
  size_t off = 0;
  auto alloc = [&](size_t bytes) -> void* {
    void* p = (char*)d_ws + off;
    off += (bytes + 255) & ~(size_t)255;
    return p;
  };
  int*      cnt      = (int*)alloc((size_t)N * 4);
  float*    dinv     = (float*)alloc((size_t)N * 4);
  int*      offs     = (int*)alloc((size_t)N * 4);
  int*      cursor   = (int*)alloc((size_t)N * 4);
  int*      chunkTot = (int*)alloc(1024);
  int*      chunkOff = (int*)alloc(1024);
  int*      csr      = (int*)alloc((size_t)E * 4);
  _Float16* tmp      = (_Float16*)alloc((size_t)N * NF * 2);
  float*    h        = (float*)alloc((size_t)N * NF * 4);
  (void)ws_size;

  (void)hipMemsetAsync(cnt, 0, (size_t)N * 4, stream);

  const int nChunks = (N + SCAN_CHUNK - 1) / SCAN_CHUNK;   // 98 for N=100k (<=128)
  const int partGrid = 128 * NPART;                        // 128 blocks per XCD

  k_count<<<partGrid, 256, 0, stream>>>(ecol, cnt, E, N);
  k_scanA<<<nChunks, 256, 0, stream>>>(cnt, chunkTot, N);
  k_scanB<<<1, 128, 0, stream>>>(chunkTot, chunkOff, nChunks);
  k_scanC<<<nChunks, 256, 0, stream>>>(cnt, chunkOff, offs, cursor, dinv, N);
  k_fill<<<partGrid, 256, 0, stream>>>(erow, ecol, cursor, csr, E, N);

  const int gemmGrid = (N + BM - 1) / BM;
  const int aggGrid = (N + 7) / 8;          // 8 nodes (half-waves) per 256-thr block

  // layer 0: x -> tmp -> h
  k_gemm<<<gemmGrid, 256, 0, stream>>>(x, W0, dinv, tmp, N);
  k_agg<<<aggGrid, 256, 0, stream>>>(tmp, offs, cursor, csr, dinv, b0, h, N);
  // layer 1
  k_gemm<<<gemmGrid, 256, 0, stream>>>(h, Whid, dinv, tmp, N);
  k_agg<<<aggGrid, 256, 0, stream>>>(tmp, offs, cursor, csr, dinv, bhid, h, N);
  // layer 2
  k_gemm<<<gemmGrid, 256, 0, stream>>>(h, Whid + 128 * 128, dinv, tmp, N);
  k_agg<<<aggGrid, 256, 0, stream>>>(tmp, offs, cursor, csr, dinv, bhid + NF, h, N);

  // pooling + head
  k_pool<<<G, 512, 0, stream>>>(h, batch, Wout, bout, out, N);
}

// Round 9
// 635.597 us; speedup vs baseline: 1.2998x; 1.2998x over previous
//
#include <hip/hip_runtime.h>
#include <math.h>

#define NF 128          // feature width (both in and out of every layer)
#define SCAN_CHUNK 1024
#define BUCK_SHIFT 9    // 512 nodes per bucket
#define BUCK_CAP 20480  // slots per bucket (avg 16384 for E=3.2M; +32 sigma)
#define NBUCK_MAX 256   // allocated buckets (used: ceil(N/512) = 196)
#define ECHUNK 2048     // edges per block-chunk in k_bucket

typedef int      vint4   __attribute__((ext_vector_type(4)));
typedef float    vfloat4 __attribute__((ext_vector_type(4)));
typedef _Float16 vhalf4  __attribute__((ext_vector_type(4)));

// ---------------------------------------------------------------------------
// Pass 1: bucketize edges by col range (512 nodes / bucket), ONE scan of the
// edge list (round-8 lesson: the 8x redundant partition scan was the cost).
// Entry = packed (c_local<<17 | r)  [valid for N <= 131072].
// LDS staging: 32 entries/bucket, flushed with one global atomicAdd per
// bucket per 2048-edge chunk -> contiguous tail appends, no write amp.
// ---------------------------------------------------------------------------
__global__ __launch_bounds__(256) void k_bucket(const int* __restrict__ row,
                                                const int* __restrict__ col,
                                                int* __restrict__ gcur,
                                                int* __restrict__ bdata, int E) {
  __shared__ int bcnt[NBUCK_MAX];
  __shared__ int bstage[NBUCK_MAX][32];
  const int tid = threadIdx.x;
  const int nChunks = (E + ECHUNK - 1) / ECHUNK;

  for (int chunk = blockIdx.x; chunk < nChunks; chunk += gridDim.x) {
    bcnt[tid] = 0;
    __syncthreads();

    const int cbase = chunk * ECHUNK;
    if (cbase + ECHUNK <= E) {
      // full chunk: vector NT loads, thread t owns edges [cbase+8t, cbase+8t+8)
      const vint4* r4 = reinterpret_cast<const vint4*>(row) + (cbase >> 2) + 2 * tid;
      const vint4* c4 = reinterpret_cast<const vint4*>(col) + (cbase >> 2) + 2 * tid;
      vint4 ra = __builtin_nontemporal_load(&r4[0]);
      vint4 rb = __builtin_nontemporal_load(&r4[1]);
      vint4 ca = __builtin_nontemporal_load(&c4[0]);
      vint4 cb = __builtin_nontemporal_load(&c4[1]);
      int rr[8] = {ra.x, ra.y, ra.z, ra.w, rb.x, rb.y, rb.z, rb.w};
      int cc[8] = {ca.x, ca.y, ca.z, ca.w, cb.x, cb.y, cb.z, cb.w};
#pragma unroll
      for (int j = 0; j < 8; ++j) {
        int b = cc[j] >> BUCK_SHIFT;
        int packed = ((cc[j] & ((1 << BUCK_SHIFT) - 1)) << 17) | rr[j];
        int pos = atomicAdd(&bcnt[b], 1);
        if (pos < 32) {
          bstage[b][pos] = packed;
        } else {                                   // overflow (rare): direct append
          int p = atomicAdd(&gcur[b], 1);
          if (p < BUCK_CAP) bdata[b * BUCK_CAP + p] = packed;
        }
      }
    } else {
      // tail chunk: scalar, coalesced
      for (int j = 0; j < 8; ++j) {
        int e = cbase + tid + j * 256;
        if (e < E) {
          int c = col[e], r = row[e];
          int b = c >> BUCK_SHIFT;
          int packed = ((c & ((1 << BUCK_SHIFT) - 1)) << 17) | r;
          int pos = atomicAdd(&bcnt[b], 1);
          if (pos < 32) {
            bstage[b][pos] = packed;
          } else {
            int p = atomicAdd(&gcur[b], 1);
            if (p < BUCK_CAP) bdata[b * BUCK_CAP + p] = packed;
          }
        }
      }
    }
    __syncthreads();

    // flush: thread tid owns bucket tid
    int k = bcnt[tid];
    if (k > 32) k = 32;
    if (k > 0) {
      int p = atomicAdd(&gcur[tid], k);
      for (int i = 0; i < k && p + i < BUCK_CAP; ++i)
        bdata[tid * BUCK_CAP + p + i] = bstage[tid][i];
    }
    __syncthreads();
  }
}

// ---------------------------------------------------------------------------
// Pass 2a: per-bucket LDS histogram -> dense cnt write (replaces k_count).
// ---------------------------------------------------------------------------
__global__ __launch_bounds__(256) void k_hist(const int* __restrict__ gcur,
                                              const int* __restrict__ bdata,
                                              int* __restrict__ cnt, int N) {
  __shared__ int hist[1 << BUCK_SHIFT];
  const int b = blockIdx.x;
  const int tid = threadIdx.x;
  hist[tid] = 0;
  hist[tid + 256] = 0;
  __syncthreads();
  int nb = gcur[b];
  if (nb > BUCK_CAP) nb = BUCK_CAP;
  const int* bd = bdata + (size_t)b * BUCK_CAP;
  for (int i = tid; i < nb; i += 256) atomicAdd(&hist[bd[i] >> 17], 1);
  __syncthreads();
  int base = b << BUCK_SHIFT;
#pragma unroll
  for (int k = 0; k < (1 << BUCK_SHIFT); k += 256) {
    int node = base + k + tid;
    if (node < N) cnt[node] = hist[k + tid];
  }
}

// ---------------------------------------------------------------------------
// Ordered exclusive prefix-sum of cnt -> offs. 3 tiny kernels over 400 KB.
// k_scanB requires nChunks <= 128 (N <= 131072).
// ---------------------------------------------------------------------------
__global__ __launch_bounds__(256) void k_scanA(const int* __restrict__ cnt,
                                               int* __restrict__ chunkTot, int N) {
  int c0 = blockIdx.x * SCAN_CHUNK + threadIdx.x * 4;
  int s = 0;
#pragma unroll
  for (int j = 0; j < 4; ++j) {
    int idx = c0 + j;
    if (idx < N) s += cnt[idx];
  }
  __shared__ int red[256];
  red[threadIdx.x] = s;
  __syncthreads();
  for (int o = 128; o > 0; o >>= 1) {
    if (threadIdx.x < o) red[threadIdx.x] += red[threadIdx.x + o];
    __syncthreads();
  }
  if (threadIdx.x == 0) chunkTot[blockIdx.x] = red[0];
}

__global__ __launch_bounds__(128) void k_scanB(const int* __restrict__ chunkTot,
                                               int* __restrict__ chunkOff, int nChunks) {
  __shared__ int buf[128];
  int t = threadIdx.x;
  int v = (t < nChunks) ? chunkTot[t] : 0;
  buf[t] = v;
  __syncthreads();
  for (int o = 1; o < 128; o <<= 1) {
    int x = buf[t];
    if (t >= o) x += buf[t - o];
    __syncthreads();
    buf[t] = x;
    __syncthreads();
  }
  if (t < nChunks) chunkOff[t] = buf[t] - v;   // exclusive
}

__global__ __launch_bounds__(256) void k_scanC(const int* __restrict__ cnt,
                                               const int* __restrict__ chunkOff,
                                               int* __restrict__ offs,
                                               float* __restrict__ dinv, int N) {
  int t = threadIdx.x;
  int c0 = blockIdx.x * SCAN_CHUNK + t * 4;
  int v[4];
  int s = 0;
#pragma unroll
  for (int j = 0; j < 4; ++j) {
    int idx = c0 + j;
    v[j] = (idx < N) ? cnt[idx] : 0;
    s += v[j];
  }
  __shared__ int buf[256];
  buf[t] = s;
  __syncthreads();
  for (int o = 1; o < 256; o <<= 1) {
    int x = buf[t];
    if (t >= o) x += buf[t - o];
    __syncthreads();
    buf[t] = x;
    __syncthreads();
  }
  int excl = buf[t] - s + chunkOff[blockIdx.x];
#pragma unroll
  for (int j = 0; j < 4; ++j) {
    int idx = c0 + j;
    if (idx < N) {
      offs[idx] = excl;
      dinv[idx] = rsqrtf((float)v[j] + 2.0f);   // deg + FILL(2.0) self-loop
      excl += v[j];
    }
  }
}

// ---------------------------------------------------------------------------
// Pass 2b: per-bucket CSR fill. One block per bucket; cursors live in LDS
// (seeded from offs); the bucket's csr range (~65 KB) is contiguous and
// written by this block only -> full lines, written once.
// ---------------------------------------------------------------------------
__global__ __launch_bounds__(256) void k_bfill(const int* __restrict__ gcur,
                                               const int* __restrict__ bdata,
                                               const int* __restrict__ offs,
                                               int* __restrict__ csr, int N) {
  __shared__ int lcur[1 << BUCK_SHIFT];
  const int b = blockIdx.x;
  const int tid = threadIdx.x;
  const int base = b << BUCK_SHIFT;
#pragma unroll
  for (int k = 0; k < (1 << BUCK_SHIFT); k += 256) {
    int node = base + k + tid;
    lcur[k + tid] = (node < N) ? offs[node] : 0;
  }
  __syncthreads();
  int nb = gcur[b];
  if (nb > BUCK_CAP) nb = BUCK_CAP;
  const int* bd = bdata + (size_t)b * BUCK_CAP;
  for (int i = tid; i < nb; i += 256) {
    int v = bd[i];
    int p = atomicAdd(&lcur[v >> 17], 1);
    csr[p] = v & 0x1FFFF;
  }
}

// ---------------------------------------------------------------------------
// GEMM: out[N,128] = dinv[row] * (H[N,128] @ W[128,128])  (f32 FMA, fp16 out)
// Tile 64 rows x 128 cols per block, BK=32 K-chunks.
// 256 threads; thread = 8 rows x 4 cols.
// ---------------------------------------------------------------------------
#define BM 64
#define BK 32
__global__ __launch_bounds__(256) void k_gemm(const float* __restrict__ H,
                                              const float* __restrict__ W,
                                              const float* __restrict__ dinv,
                                              _Float16* __restrict__ out, int nRows) {
  __shared__ float Wl[BK][NF];       // 16 KB
  __shared__ float Hl[BM][BK + 4];   // stride 36 floats (144 B, 16B-aligned), 9 KB

  const int tid = threadIdx.x;
  const int c4 = (tid & 31) * 4;     // output col base
  const int rg = (tid >> 5) * 8;     // row-group base (8 rows per thread)
  const int rowBase = blockIdx.x * BM;

  float acc[8][4];
#pragma unroll
  for (int j = 0; j < 8; ++j)
#pragma unroll
    for (int c = 0; c < 4; ++c) acc[j][c] = 0.f;

  for (int kc = 0; kc < NF; kc += BK) {
    __syncthreads();   // protect LDS from previous chunk's readers
    // stage W chunk [BK][128] (contiguous copy)
    {
      const float4* src = reinterpret_cast<const float4*>(W + (size_t)kc * NF);
      float4* dst = reinterpret_cast<float4*>(&Wl[0][0]);
      for (int i = tid; i < BK * NF / 4; i += 256) dst[i] = src[i];
    }
    // stage H chunk [BM][BK]
    {
      int r0 = tid >> 3;
      int cs = (tid & 7) * 4;
#pragma unroll
      for (int half = 0; half < 2; ++half) {
        int r = r0 + half * 32;
        int gr = rowBase + r;
        float4 v = make_float4(0.f, 0.f, 0.f, 0.f);
        if (gr < nRows)
          v = *reinterpret_cast<const float4*>(H + (size_t)gr * NF + kc + cs);
        *reinterpret_cast<float4*>(&Hl[r][cs]) = v;
      }
    }
    __syncthreads();

#pragma unroll
    for (int k = 0; k < BK; k += 4) {
      float4 w0 = *reinterpret_cast<float4*>(&Wl[k + 0][c4]);
      float4 w1 = *reinterpret_cast<float4*>(&Wl[k + 1][c4]);
      float4 w2 = *reinterpret_cast<float4*>(&Wl[k + 2][c4]);
      float4 w3 = *reinterpret_cast<float4*>(&Wl[k + 3][c4]);
#pragma unroll
      for (int j = 0; j < 8; ++j) {
        float4 hv = *reinterpret_cast<float4*>(&Hl[rg + j][k]);   // broadcast read
        acc[j][0] = fmaf(hv.x, w0.x, acc[j][0]);
        acc[j][1] = fmaf(hv.x, w0.y, acc[j][1]);
        acc[j][2] = fmaf(hv.x, w0.z, acc[j][2]);
        acc[j][3] = fmaf(hv.x, w0.w, acc[j][3]);
        acc[j][0] = fmaf(hv.y, w1.x, acc[j][0]);
        acc[j][1] = fmaf(hv.y, w1.y, acc[j][1]);
        acc[j][2] = fmaf(hv.y, w1.z, acc[j][2]);
        acc[j][3] = fmaf(hv.y, w1.w, acc[j][3]);
        acc[j][0] = fmaf(hv.z, w2.x, acc[j][0]);
        acc[j][1] = fmaf(hv.z, w2.y, acc[j][1]);
        acc[j][2] = fmaf(hv.z, w2.z, acc[j][2]);
        acc[j][3] = fmaf(hv.z, w2.w, acc[j][3]);
        acc[j][0] = fmaf(hv.w, w3.x, acc[j][0]);
        acc[j][1] = fmaf(hv.w, w3.y, acc[j][1]);
        acc[j][2] = fmaf(hv.w, w3.z, acc[j][2]);
        acc[j][3] = fmaf(hv.w, w3.w, acc[j][3]);
      }
    }
  }

#pragma unroll
  for (int j = 0; j < 8; ++j) {
    int gr = rowBase + rg + j;
    if (gr < nRows) {
      float dv = dinv[gr];
      vhalf4 v;
      v.x = (_Float16)(dv * acc[j][0]);
      v.y = (_Float16)(dv * acc[j][1]);
      v.z = (_Float16)(dv * acc[j][2]);
      v.w = (_Float16)(dv * acc[j][3]);
      *reinterpret_cast<vhalf4*>(out + (size_t)gr * NF + c4) = v;
    }
  }
}

// ---------------------------------------------------------------------------
// Aggregation: h[v] = tanh( dinv[v]*( sum_src tmp'[src] + 2*tmp'[v] ) + b )
// tmp' is fp16, pre-scaled by dinv (see k_gemm). f32 accumulation.
// Half-wave (32 lanes) per node, half4 (8 B) per lane = 256 B/row per instr.
// Edge loop unrolled x8, CSR read as 4-edge int4 nontemporal.
// ---------------------------------------------------------------------------
__device__ __forceinline__ float4 h2f(vhalf4 v) {
  return make_float4((float)v.x, (float)v.y, (float)v.z, (float)v.w);
}
__device__ __forceinline__ float4 add4(float4 a, float4 acc) {
  acc.x += a.x; acc.y += a.y; acc.z += a.z; acc.w += a.w;
  return acc;
}

__global__ __launch_bounds__(256) void k_agg(const _Float16* __restrict__ tmp,
                                             const int* __restrict__ offs,
                                             const int* __restrict__ cnt,
                                             const int* __restrict__ csr,
                                             const float* __restrict__ dinv,
                                             const float* __restrict__ bias,
                                             float* __restrict__ hout, int N) {
  int node = (blockIdx.x * 256 + threadIdx.x) >> 5;
  if (node >= N) return;
  int lane = threadIdx.x & 31;

  float dv = dinv[node];

  const vhalf4* t4 = reinterpret_cast<const vhalf4*>(tmp);
  float4 hv = h2f(t4[(size_t)node * 32 + lane]);
  float4 acc = make_float4(2.f * hv.x, 2.f * hv.y, 2.f * hv.z, 2.f * hv.w);

  int s = offs[node], e = s + cnt[node];
  int i = s;

  // align i to 4 so vint4 (4-edge) loads are 16B-aligned
  for (; (i & 3) && i < e; ++i) {
    float4 a = h2f(t4[(size_t)csr[i] * 32 + lane]);
    acc = add4(a, acc);
  }

  const vint4* cp = reinterpret_cast<const vint4*>(csr);
  for (; i + 8 <= e; i += 8) {
    vint4 p0 = __builtin_nontemporal_load(&cp[(i >> 2) + 0]);
    vint4 p1 = __builtin_nontemporal_load(&cp[(i >> 2) + 1]);
    float4 a0 = h2f(t4[(size_t)p0.x * 32 + lane]);
    float4 a1 = h2f(t4[(size_t)p0.y * 32 + lane]);
    float4 a2 = h2f(t4[(size_t)p0.z * 32 + lane]);
    float4 a3 = h2f(t4[(size_t)p0.w * 32 + lane]);
    float4 a4 = h2f(t4[(size_t)p1.x * 32 + lane]);
    float4 a5 = h2f(t4[(size_t)p1.y * 32 + lane]);
    float4 a6 = h2f(t4[(size_t)p1.z * 32 + lane]);
    float4 a7 = h2f(t4[(size_t)p1.w * 32 + lane]);
    acc = add4(a0, acc); acc = add4(a1, acc);
    acc = add4(a2, acc); acc = add4(a3, acc);
    acc = add4(a4, acc); acc = add4(a5, acc);
    acc = add4(a6, acc); acc = add4(a7, acc);
  }
  for (; i + 4 <= e; i += 4) {
    vint4 p = __builtin_nontemporal_load(&cp[i >> 2]);
    float4 a0 = h2f(t4[(size_t)p.x * 32 + lane]);
    float4 a1 = h2f(t4[(size_t)p.y * 32 + lane]);
    float4 a2 = h2f(t4[(size_t)p.z * 32 + lane]);
    float4 a3 = h2f(t4[(size_t)p.w * 32 + lane]);
    acc = add4(a0, acc); acc = add4(a1, acc);
    acc = add4(a2, acc); acc = add4(a3, acc);
  }
  for (; i < e; ++i) {
    float4 a = h2f(t4[(size_t)csr[i] * 32 + lane]);
    acc = add4(a, acc);
  }

  float4 b4 = reinterpret_cast<const float4*>(bias)[lane];
  vfloat4 r;
  r.x = tanhf(fmaf(dv, acc.x, b4.x));
  r.y = tanhf(fmaf(dv, acc.y, b4.y));
  r.z = tanhf(fmaf(dv, acc.z, b4.z));
  r.w = tanhf(fmaf(dv, acc.w, b4.w));
  vfloat4* outp = reinterpret_cast<vfloat4*>(hout) + ((size_t)node * 32 + lane);
  __builtin_nontemporal_store(r, outp);
}

// ---------------------------------------------------------------------------
// Pool (segment max + mean over sorted batch_index) fused with the linear head.
// One block (512 threads = 4 row-stripes of 128 features) per graph.
// ---------------------------------------------------------------------------
__global__ __launch_bounds__(512) void k_pool(const float* __restrict__ h,
                                              const int* __restrict__ batch,
                                              const float* __restrict__ Wout,
                                              const float* __restrict__ bout,
                                              float* __restrict__ out, int N) {
  int g = blockIdx.x;

  // lower_bound(batch, g) and lower_bound(batch, g+1): all threads redundantly
  int lo = 0, hi = N;
  while (lo < hi) { int mid = (lo + hi) >> 1; if (batch[mid] < g) lo = mid + 1; else hi = mid; }
  int s = lo;
  int lo2 = s, hi2 = N;
  while (lo2 < hi2) { int mid = (lo2 + hi2) >> 1; if (batch[mid] < g + 1) lo2 = mid + 1; else hi2 = mid; }
  int e = lo2;

  int f = threadIdx.x & 127;
  int stripe = threadIdx.x >> 7;   // 0..3

  float mx = -INFINITY, sm = 0.f;
  for (int n = s + stripe; n < e; n += 4) {
    float v = h[(size_t)n * NF + f];
    mx = fmaxf(mx, v);
    sm += v;
  }

  __shared__ float smx[4][NF];
  __shared__ float ssm[4][NF];
  smx[stripe][f] = mx;
  ssm[stripe][f] = sm;
  __syncthreads();

  if (stripe == 0) {
    mx = fmaxf(fmaxf(smx[0][f], smx[1][f]), fmaxf(smx[2][f], smx[3][f]));
    sm = ssm[0][f] + ssm[1][f] + ssm[2][f] + ssm[3][f];

    int cnt = e - s;
    float mean = sm / fmaxf((float)cnt, 1.0f);
    if (cnt == 0) mx = 0.f;

    float part = mx * Wout[f] + mean * Wout[NF + f];

    // reduce 128 threads = 2 waves
    for (int o = 32; o > 0; o >>= 1) part += __shfl_down(part, o);
    __shared__ float wsum[2];
    if ((threadIdx.x & 63) == 0) wsum[threadIdx.x >> 6] = part;
    __syncthreads();
    if (threadIdx.x == 0) out[g] = wsum[0] + wsum[1] + bout[0];
  }
}

// ---------------------------------------------------------------------------
// Driver
// ---------------------------------------------------------------------------
extern "C" void kernel_launch(void* const* d_in, const int* in_sizes, int n_in,
                              void* d_out, int out_size, void* d_ws, size_t ws_size,
                              hipStream_t stream) {
  const float* x     = (const float*)d_in[0];
  const int*   eidx  = (const int*)d_in[1];     // [2][E]
  const int*   batch = (const int*)d_in[2];     // [N]
  const float* W0    = (const float*)d_in[3];
  const float* b0    = (const float*)d_in[4];
  const float* Whid  = (const float*)d_in[5];   // [2][128][128]
  const float* bhid  = (const float*)d_in[6];   // [2][128]
  const float* Wout  = (const float*)d_in[7];   // [256]
  const float* bout  = (const float*)d_in[8];   // [1]
  float* out = (float*)d_out;

  const int N = in_sizes[0] / NF;
  const int E = in_sizes[1] / 2;
  const int G = out_size;

  const int* erow = eidx;
  const int* ecol = eidx + E;

  // workspace layout (256B aligned)
  size_t off = 0;
  auto alloc = [&](size_t bytes) -> void* {
    void* p = (char*)d_ws + off;
    off += (bytes + 255) & ~(size_t)255;
    return p;
  };
  int*      gcur     = (int*)alloc(NBUCK_MAX * 4);
  int*      cnt      = (int*)alloc((size_t)N * 4);
  float*    dinv     = (float*)alloc((size_t)N * 4);
  int*      offs     = (int*)alloc((size_t)N * 4);
  int*      chunkTot = (int*)alloc(1024);
  int*      chunkOff = (int*)alloc(1024);
  int*      bdata    = (int*)alloc((size_t)NBUCK_MAX * BUCK_CAP * 4);  // 21 MB
  int*      csr      = (int*)alloc((size_t)E * 4);
  _Float16* tmp      = (_Float16*)alloc((size_t)N * NF * 2);
  float*    h        = (float*)alloc((size_t)N * NF * 4);
  (void)ws_size;

  (void)hipMemsetAsync(gcur, 0, NBUCK_MAX * 4, stream);

  const int nChunks = (N + SCAN_CHUNK - 1) / SCAN_CHUNK;     // 98 for N=100k
  const int nbuck = (N + (1 << BUCK_SHIFT) - 1) >> BUCK_SHIFT; // 196 for N=100k

  k_bucket<<<512, 256, 0, stream>>>(erow, ecol, gcur, bdata, E);
  k_hist<<<nbuck, 256, 0, stream>>>(gcur, bdata, cnt, N);
  k_scanA<<<nChunks, 256, 0, stream>>>(cnt, chunkTot, N);
  k_scanB<<<1, 128, 0, stream>>>(chunkTot, chunkOff, nChunks);
  k_scanC<<<nChunks, 256, 0, stream>>>(cnt, chunkOff, offs, dinv, N);
  k_bfill<<<nbuck, 256, 0, stream>>>(gcur, bdata, offs, csr, N);

  const int gemmGrid = (N + BM - 1) / BM;
  const int aggGrid = (N + 7) / 8;          // 8 nodes (half-waves) per 256-thr block

  // layer 0: x -> tmp -> h
  k_gemm<<<gemmGrid, 256, 0, stream>>>(x, W0, dinv, tmp, N);
  k_agg<<<aggGrid, 256, 0, stream>>>(tmp, offs, cnt, csr, dinv, b0, h, N);
  // layer 1
  k_gemm<<<gemmGrid, 256, 0, stream>>>(h, Whid, dinv, tmp, N);
  k_agg<<<aggGrid, 256, 0, stream>>>(tmp, offs, cnt, csr, dinv, bhid, h, N);
  // layer 2
  k_gemm<<<gemmGrid, 256, 0, stream>>>(h, Whid + 128 * 128, dinv, tmp, N);
  k_agg<<<aggGrid, 256, 0, stream>>>(tmp, offs, cnt, csr, dinv, bhid + NF, h, N);

  // pooling + head
  k_pool<<<G, 512, 0, stream>>>(h, batch, Wout, bout, out, N);
}

// Round 10
// 553.911 us; speedup vs baseline: 1.4915x; 1.1475x over previous
//
#include <hip/hip_runtime.h>
#include <math.h>

#define NF 128          // feature width (both in and out of every layer)
#define SCAN_CHUNK 1024
#define BUCK_SHIFT 9    // 512 nodes per bucket
#define BUCK_CAP 20480  // slots per bucket (avg 16384 for E=3.2M; +32 sigma)
#define NBUCK_MAX 256   // allocated buckets (used: ceil(N/512) = 196)
#define ECHUNK 2048     // edges per block-chunk in k_bucket

typedef int      vint4   __attribute__((ext_vector_type(4)));
typedef float    vfloat4 __attribute__((ext_vector_type(4)));
typedef float    f32x4   __attribute__((ext_vector_type(4)));
typedef _Float16 vhalf4  __attribute__((ext_vector_type(4)));
typedef _Float16 vhalf8  __attribute__((ext_vector_type(8)));

// ---------------------------------------------------------------------------
// Pass 1: bucketize edges by col range (512 nodes / bucket), ONE scan of the
// edge list. Entry = packed (c_local<<17 | r)  [valid for N <= 131072].
// ---------------------------------------------------------------------------
__global__ __launch_bounds__(256) void k_bucket(const int* __restrict__ row,
                                                const int* __restrict__ col,
                                                int* __restrict__ gcur,
                                                int* __restrict__ bdata, int E) {
  __shared__ int bcnt[NBUCK_MAX];
  __shared__ int bstage[NBUCK_MAX][32];
  const int tid = threadIdx.x;
  const int nChunks = (E + ECHUNK - 1) / ECHUNK;

  for (int chunk = blockIdx.x; chunk < nChunks; chunk += gridDim.x) {
    bcnt[tid] = 0;
    __syncthreads();

    const int cbase = chunk * ECHUNK;
    if (cbase + ECHUNK <= E) {
      const vint4* r4 = reinterpret_cast<const vint4*>(row) + (cbase >> 2) + 2 * tid;
      const vint4* c4 = reinterpret_cast<const vint4*>(col) + (cbase >> 2) + 2 * tid;
      vint4 ra = __builtin_nontemporal_load(&r4[0]);
      vint4 rb = __builtin_nontemporal_load(&r4[1]);
      vint4 ca = __builtin_nontemporal_load(&c4[0]);
      vint4 cb = __builtin_nontemporal_load(&c4[1]);
      int rr[8] = {ra.x, ra.y, ra.z, ra.w, rb.x, rb.y, rb.z, rb.w};
      int cc[8] = {ca.x, ca.y, ca.z, ca.w, cb.x, cb.y, cb.z, cb.w};
#pragma unroll
      for (int j = 0; j < 8; ++j) {
        int b = cc[j] >> BUCK_SHIFT;
        int packed = ((cc[j] & ((1 << BUCK_SHIFT) - 1)) << 17) | rr[j];
        int pos = atomicAdd(&bcnt[b], 1);
        if (pos < 32) {
          bstage[b][pos] = packed;
        } else {                                   // overflow (rare): direct append
          int p = atomicAdd(&gcur[b], 1);
          if (p < BUCK_CAP) bdata[b * BUCK_CAP + p] = packed;
        }
      }
    } else {
      for (int j = 0; j < 8; ++j) {
        int e = cbase + tid + j * 256;
        if (e < E) {
          int c = col[e], r = row[e];
          int b = c >> BUCK_SHIFT;
          int packed = ((c & ((1 << BUCK_SHIFT) - 1)) << 17) | r;
          int pos = atomicAdd(&bcnt[b], 1);
          if (pos < 32) {
            bstage[b][pos] = packed;
          } else {
            int p = atomicAdd(&gcur[b], 1);
            if (p < BUCK_CAP) bdata[b * BUCK_CAP + p] = packed;
          }
        }
      }
    }
    __syncthreads();

    int k = bcnt[tid];
    if (k > 32) k = 32;
    if (k > 0) {
      int p = atomicAdd(&gcur[tid], k);
      for (int i = 0; i < k && p + i < BUCK_CAP; ++i)
        bdata[tid * BUCK_CAP + p + i] = bstage[tid][i];
    }
    __syncthreads();
  }
}

// ---------------------------------------------------------------------------
// Pass 2a: per-bucket LDS histogram -> dense cnt write.
// ---------------------------------------------------------------------------
__global__ __launch_bounds__(256) void k_hist(const int* __restrict__ gcur,
                                              const int* __restrict__ bdata,
                                              int* __restrict__ cnt, int N) {
  __shared__ int hist[1 << BUCK_SHIFT];
  const int b = blockIdx.x;
  const int tid = threadIdx.x;
  hist[tid] = 0;
  hist[tid + 256] = 0;
  __syncthreads();
  int nb = gcur[b];
  if (nb > BUCK_CAP) nb = BUCK_CAP;
  const int* bd = bdata + (size_t)b * BUCK_CAP;
  for (int i = tid; i < nb; i += 256) atomicAdd(&hist[bd[i] >> 17], 1);
  __syncthreads();
  int base = b << BUCK_SHIFT;
#pragma unroll
  for (int k = 0; k < (1 << BUCK_SHIFT); k += 256) {
    int node = base + k + tid;
    if (node < N) cnt[node] = hist[k + tid];
  }
}

// ---------------------------------------------------------------------------
// Ordered exclusive prefix-sum of cnt -> offs. k_scanB needs nChunks <= 128.
// ---------------------------------------------------------------------------
__global__ __launch_bounds__(256) void k_scanA(const int* __restrict__ cnt,
                                               int* __restrict__ chunkTot, int N) {
  int c0 = blockIdx.x * SCAN_CHUNK + threadIdx.x * 4;
  int s = 0;
#pragma unroll
  for (int j = 0; j < 4; ++j) {
    int idx = c0 + j;
    if (idx < N) s += cnt[idx];
  }
  __shared__ int red[256];
  red[threadIdx.x] = s;
  __syncthreads();
  for (int o = 128; o > 0; o >>= 1) {
    if (threadIdx.x < o) red[threadIdx.x] += red[threadIdx.x + o];
    __syncthreads();
  }
  if (threadIdx.x == 0) chunkTot[blockIdx.x] = red[0];
}

__global__ __launch_bounds__(128) void k_scanB(const int* __restrict__ chunkTot,
                                               int* __restrict__ chunkOff, int nChunks) {
  __shared__ int buf[128];
  int t = threadIdx.x;
  int v = (t < nChunks) ? chunkTot[t] : 0;
  buf[t] = v;
  __syncthreads();
  for (int o = 1; o < 128; o <<= 1) {
    int x = buf[t];
    if (t >= o) x += buf[t - o];
    __syncthreads();
    buf[t] = x;
    __syncthreads();
  }
  if (t < nChunks) chunkOff[t] = buf[t] - v;   // exclusive
}

__global__ __launch_bounds__(256) void k_scanC(const int* __restrict__ cnt,
                                               const int* __restrict__ chunkOff,
                                               int* __restrict__ offs,
                                               float* __restrict__ dinv, int N) {
  int t = threadIdx.x;
  int c0 = blockIdx.x * SCAN_CHUNK + t * 4;
  int v[4];
  int s = 0;
#pragma unroll
  for (int j = 0; j < 4; ++j) {
    int idx = c0 + j;
    v[j] = (idx < N) ? cnt[idx] : 0;
    s += v[j];
  }
  __shared__ int buf[256];
  buf[t] = s;
  __syncthreads();
  for (int o = 1; o < 256; o <<= 1) {
    int x = buf[t];
    if (t >= o) x += buf[t - o];
    __syncthreads();
    buf[t] = x;
    __syncthreads();
  }
  int excl = buf[t] - s + chunkOff[blockIdx.x];
#pragma unroll
  for (int j = 0; j < 4; ++j) {
    int idx = c0 + j;
    if (idx < N) {
      offs[idx] = excl;
      dinv[idx] = rsqrtf((float)v[j] + 2.0f);   // deg + FILL(2.0) self-loop
      excl += v[j];
    }
  }
}

// ---------------------------------------------------------------------------
// Pass 2b: per-bucket CSR fill; cursors in LDS, contiguous csr range/block.
// ---------------------------------------------------------------------------
__global__ __launch_bounds__(256) void k_bfill(const int* __restrict__ gcur,
                                               const int* __restrict__ bdata,
                                               const int* __restrict__ offs,
                                               int* __restrict__ csr, int N) {
  __shared__ int lcur[1 << BUCK_SHIFT];
  const int b = blockIdx.x;
  const int tid = threadIdx.x;
  const int base = b << BUCK_SHIFT;
#pragma unroll
  for (int k = 0; k < (1 << BUCK_SHIFT); k += 256) {
    int node = base + k + tid;
    lcur[k + tid] = (node < N) ? offs[node] : 0;
  }
  __syncthreads();
  int nb = gcur[b];
  if (nb > BUCK_CAP) nb = BUCK_CAP;
  const int* bd = bdata + (size_t)b * BUCK_CAP;
  for (int i = tid; i < nb; i += 256) {
    int v = bd[i];
    int p = atomicAdd(&lcur[v >> 17], 1);
    csr[p] = v & 0x1FFFF;
  }
}

// ---------------------------------------------------------------------------
// One-time converts: W (3 layers) f32 -> fp16 TRANSPOSED [col][k]; x -> fp16.
// ---------------------------------------------------------------------------
__global__ __launch_bounds__(256) void k_wcvt(const float* __restrict__ W0,
                                              const float* __restrict__ Whid,
                                              _Float16* __restrict__ wt) {
  int g = blockIdx.x * 1024 + threadIdx.x * 4;
#pragma unroll
  for (int j = 0; j < 4; ++j) {
    int idx = g + j;                       // 0 .. 49151
    int layer = idx >> 14;
    int within = idx & 16383;              // = col*128 + k (dst order)
    int c = within >> 7, k = within & 127;
    const float* src = (layer == 0) ? W0 : Whid + (layer - 1) * 16384;
    wt[idx] = (_Float16)src[k * 128 + c];
  }
}

__global__ __launch_bounds__(256) void k_xcvt(const float* __restrict__ x,
                                              _Float16* __restrict__ xh, int n4) {
  int i = blockIdx.x * blockDim.x + threadIdx.x;
  int stride = gridDim.x * blockDim.x;
  const vfloat4* x4 = reinterpret_cast<const vfloat4*>(x);
  vhalf4* o4 = reinterpret_cast<vhalf4*>(xh);
  for (; i < n4; i += stride) {
    vfloat4 v = __builtin_nontemporal_load(&x4[i]);
    vhalf4 o;
    o.x = (_Float16)v.x; o.y = (_Float16)v.y;
    o.z = (_Float16)v.z; o.w = (_Float16)v.w;
    __builtin_nontemporal_store(o, &o4[i]);
  }
}

// ---------------------------------------------------------------------------
// MFMA GEMM: out[N,128] = dinv[row] * (Hh[N,128] @ W[128,128]), all fp16 in,
// f32 accumulate (v_mfma_f32_16x16x32_f16), fp16 out.
// Block = 256 thr = 4 waves; wave owns 16 rows x 128 cols = 8 col-tiles.
// Wt (fp16, [col][k]) staged in LDS with +8 pad (bank-spread).
// Fragment layouts: A row=l&15,k=(l>>4)*8+j; B col=l&15,k=(l>>4)*8+j;
// C col=l&15,row=(l>>4)*4+reg (m89-verified, dtype-independent).
// ---------------------------------------------------------------------------
__global__ __launch_bounds__(256) void k_gemm(const _Float16* __restrict__ Hh,
                                              const _Float16* __restrict__ Wt,
                                              const float* __restrict__ dinv,
                                              _Float16* __restrict__ out, int nRows) {
  __shared__ _Float16 Wl[128][136];   // 34.8 KB

  const int tid = threadIdx.x;
  for (int i = tid; i < 128 * 16; i += 256) {
    int r = i >> 4, seg = i & 15;
    *reinterpret_cast<vhalf8*>(&Wl[r][seg * 8]) =
        *reinterpret_cast<const vhalf8*>(Wt + r * 128 + seg * 8);
  }
  __syncthreads();

  const int l = tid & 63;
  const int wv = tid >> 6;
  const int rowBase = blockIdx.x * 64 + wv * 16;
  const int lrow = l & 15;
  const int lk8 = (l >> 4) * 8;

  vhalf8 a[4];
  int arow = rowBase + lrow;
  if (arow < nRows) {
    const _Float16* ap = Hh + (size_t)arow * 128 + lk8;
#pragma unroll
    for (int kc = 0; kc < 4; ++kc)
      a[kc] = *reinterpret_cast<const vhalf8*>(ap + kc * 32);
  } else {
#pragma unroll
    for (int kc = 0; kc < 4; ++kc)
#pragma unroll
      for (int j = 0; j < 8; ++j) a[kc][j] = (_Float16)0.f;
  }

  f32x4 acc[8];
#pragma unroll
  for (int ct = 0; ct < 8; ++ct) acc[ct] = (f32x4)(0.f);

#pragma unroll
  for (int kc = 0; kc < 4; ++kc) {
#pragma unroll
    for (int ct = 0; ct < 8; ++ct) {
      vhalf8 b = *reinterpret_cast<const vhalf8*>(&Wl[ct * 16 + lrow][kc * 32 + lk8]);
      acc[ct] = __builtin_amdgcn_mfma_f32_16x16x32_f16(a[kc], b, acc[ct], 0, 0, 0);
    }
  }

  const int r0 = rowBase + (l >> 4) * 4;
  float dv[4];
#pragma unroll
  for (int r = 0; r < 4; ++r) dv[r] = (r0 + r < nRows) ? dinv[r0 + r] : 0.f;
#pragma unroll
  for (int ct = 0; ct < 8; ++ct) {
#pragma unroll
    for (int r = 0; r < 4; ++r) {
      int row = r0 + r;
      if (row < nRows)
        out[(size_t)row * 128 + ct * 16 + lrow] = (_Float16)(dv[r] * acc[ct][r]);
    }
  }
}

// ---------------------------------------------------------------------------
// Aggregation: h[v] = tanh( dinv[v]*( sum_src tmp'[src] + 2*tmp'[v] ) + b )
// tmp' fp16 (dinv-pre-scaled); f32 accumulation; fp16 output.
// Half-wave per node, half4 per lane; edge loop x8, CSR int4 NT loads.
// ---------------------------------------------------------------------------
__device__ __forceinline__ float4 h2f(vhalf4 v) {
  return make_float4((float)v.x, (float)v.y, (float)v.z, (float)v.w);
}
__device__ __forceinline__ float4 add4(float4 a, float4 acc) {
  acc.x += a.x; acc.y += a.y; acc.z += a.z; acc.w += a.w;
  return acc;
}

__global__ __launch_bounds__(256) void k_agg(const _Float16* __restrict__ tmp,
                                             const int* __restrict__ offs,
                                             const int* __restrict__ cnt,
                                             const int* __restrict__ csr,
                                             const float* __restrict__ dinv,
                                             const float* __restrict__ bias,
                                             _Float16* __restrict__ hout, int N) {
  int node = (blockIdx.x * 256 + threadIdx.x) >> 5;
  if (node >= N) return;
  int lane = threadIdx.x & 31;

  float dv = dinv[node];

  const vhalf4* t4 = reinterpret_cast<const vhalf4*>(tmp);
  float4 hv = h2f(t4[(size_t)node * 32 + lane]);
  float4 acc = make_float4(2.f * hv.x, 2.f * hv.y, 2.f * hv.z, 2.f * hv.w);

  int s = offs[node], e = s + cnt[node];
  int i = s;

  for (; (i & 3) && i < e; ++i) {
    float4 a = h2f(t4[(size_t)csr[i] * 32 + lane]);
    acc = add4(a, acc);
  }

  const vint4* cp = reinterpret_cast<const vint4*>(csr);
  for (; i + 8 <= e; i += 8) {
    vint4 p0 = __builtin_nontemporal_load(&cp[(i >> 2) + 0]);
    vint4 p1 = __builtin_nontemporal_load(&cp[(i >> 2) + 1]);
    float4 a0 = h2f(t4[(size_t)p0.x * 32 + lane]);
    float4 a1 = h2f(t4[(size_t)p0.y * 32 + lane]);
    float4 a2 = h2f(t4[(size_t)p0.z * 32 + lane]);
    float4 a3 = h2f(t4[(size_t)p0.w * 32 + lane]);
    float4 a4 = h2f(t4[(size_t)p1.x * 32 + lane]);
    float4 a5 = h2f(t4[(size_t)p1.y * 32 + lane]);
    float4 a6 = h2f(t4[(size_t)p1.z * 32 + lane]);
    float4 a7 = h2f(t4[(size_t)p1.w * 32 + lane]);
    acc = add4(a0, acc); acc = add4(a1, acc);
    acc = add4(a2, acc); acc = add4(a3, acc);
    acc = add4(a4, acc); acc = add4(a5, acc);
    acc = add4(a6, acc); acc = add4(a7, acc);
  }
  for (; i + 4 <= e; i += 4) {
    vint4 p = __builtin_nontemporal_load(&cp[i >> 2]);
    float4 a0 = h2f(t4[(size_t)p.x * 32 + lane]);
    float4 a1 = h2f(t4[(size_t)p.y * 32 + lane]);
    float4 a2 = h2f(t4[(size_t)p.z * 32 + lane]);
    float4 a3 = h2f(t4[(size_t)p.w * 32 + lane]);
    acc = add4(a0, acc); acc = add4(a1, acc);
    acc = add4(a2, acc); acc = add4(a3, acc);
  }
  for (; i < e; ++i) {
    float4 a = h2f(t4[(size_t)csr[i] * 32 + lane]);
    acc = add4(a, acc);
  }

  float4 b4 = reinterpret_cast<const float4*>(bias)[lane];
  vhalf4 r;
  r.x = (_Float16)tanhf(fmaf(dv, acc.x, b4.x));
  r.y = (_Float16)tanhf(fmaf(dv, acc.y, b4.y));
  r.z = (_Float16)tanhf(fmaf(dv, acc.z, b4.z));
  r.w = (_Float16)tanhf(fmaf(dv, acc.w, b4.w));
  __builtin_nontemporal_store(r, &reinterpret_cast<vhalf4*>(hout)[(size_t)node * 32 + lane]);
}

// ---------------------------------------------------------------------------
// Pool (segment max + mean, h fp16) fused with the linear head.
// One block (512 threads = 4 row-stripes of 128 features) per graph.
// ---------------------------------------------------------------------------
__global__ __launch_bounds__(512) void k_pool(const _Float16* __restrict__ h,
                                              const int* __restrict__ batch,
                                              const float* __restrict__ Wout,
                                              const float* __restrict__ bout,
                                              float* __restrict__ out, int N) {
  int g = blockIdx.x;

  int lo = 0, hi = N;
  while (lo < hi) { int mid = (lo + hi) >> 1; if (batch[mid] < g) lo = mid + 1; else hi = mid; }
  int s = lo;
  int lo2 = s, hi2 = N;
  while (lo2 < hi2) { int mid = (lo2 + hi2) >> 1; if (batch[mid] < g + 1) lo2 = mid + 1; else hi2 = mid; }
  int e = lo2;

  int f = threadIdx.x & 127;
  int stripe = threadIdx.x >> 7;   // 0..3

  float mx = -INFINITY, sm = 0.f;
  for (int n = s + stripe; n < e; n += 4) {
    float v = (float)h[(size_t)n * NF + f];
    mx = fmaxf(mx, v);
    sm += v;
  }

  __shared__ float smx[4][NF];
  __shared__ float ssm[4][NF];
  smx[stripe][f] = mx;
  ssm[stripe][f] = sm;
  __syncthreads();

  if (stripe == 0) {
    mx = fmaxf(fmaxf(smx[0][f], smx[1][f]), fmaxf(smx[2][f], smx[3][f]));
    sm = ssm[0][f] + ssm[1][f] + ssm[2][f] + ssm[3][f];

    int cnt = e - s;
    float mean = sm / fmaxf((float)cnt, 1.0f);
    if (cnt == 0) mx = 0.f;

    float part = mx * Wout[f] + mean * Wout[NF + f];

    for (int o = 32; o > 0; o >>= 1) part += __shfl_down(part, o);
    __shared__ float wsum[2];
    if ((threadIdx.x & 63) == 0) wsum[threadIdx.x >> 6] = part;
    __syncthreads();
    if (threadIdx.x == 0) out[g] = wsum[0] + wsum[1] + bout[0];
  }
}

// ---------------------------------------------------------------------------
// Driver
// ---------------------------------------------------------------------------
extern "C" void kernel_launch(void* const* d_in, const int* in_sizes, int n_in,
                              void* d_out, int out_size, void* d_ws, size_t ws_size,
                              hipStream_t stream) {
  const float* x     = (const float*)d_in[0];
  const int*   eidx  = (const int*)d_in[1];     // [2][E]
  const int*   batch = (const int*)d_in[2];     // [N]
  const float* W0    = (const float*)d_in[3];
  const float* b0    = (const float*)d_in[4];
  const float* Whid  = (const float*)d_in[5];   // [2][128][128]
  const float* bhid  = (const float*)d_in[6];   // [2][128]
  const float* Wout  = (const float*)d_in[7];   // [256]
  const float* bout  = (const float*)d_in[8];   // [1]
  float* out = (float*)d_out;

  const int N = in_sizes[0] / NF;
  const int E = in_sizes[1] / 2;
  const int G = out_size;

  const int* erow = eidx;
  const int* ecol = eidx + E;

  // workspace layout (256B aligned)
  size_t off = 0;
  auto alloc = [&](size_t bytes) -> void* {
    void* p = (char*)d_ws + off;
    off += (bytes + 255) & ~(size_t)255;
    return p;
  };
  int*      gcur     = (int*)alloc(NBUCK_MAX * 4);
  int*      cnt      = (int*)alloc((size_t)N * 4);
  float*    dinv     = (float*)alloc((size_t)N * 4);
  int*      offs     = (int*)alloc((size_t)N * 4);
  int*      chunkTot = (int*)alloc(1024);
  int*      chunkOff = (int*)alloc(1024);
  int*      bdata    = (int*)alloc((size_t)NBUCK_MAX * BUCK_CAP * 4);  // 21 MB
  int*      csr      = (int*)alloc((size_t)E * 4);
  _Float16* wt       = (_Float16*)alloc(3 * 16384 * 2);                // 96 KB
  _Float16* xh       = (_Float16*)alloc((size_t)N * NF * 2);
  _Float16* tmp      = (_Float16*)alloc((size_t)N * NF * 2);
  _Float16* h        = (_Float16*)alloc((size_t)N * NF * 2);
  (void)ws_size;

  (void)hipMemsetAsync(gcur, 0, NBUCK_MAX * 4, stream);

  const int nChunks = (N + SCAN_CHUNK - 1) / SCAN_CHUNK;       // 98 for N=100k
  const int nbuck = (N + (1 << BUCK_SHIFT) - 1) >> BUCK_SHIFT; // 196 for N=100k

  k_bucket<<<512, 256, 0, stream>>>(erow, ecol, gcur, bdata, E);
  k_hist<<<nbuck, 256, 0, stream>>>(gcur, bdata, cnt, N);
  k_scanA<<<nChunks, 256, 0, stream>>>(cnt, chunkTot, N);
  k_scanB<<<1, 128, 0, stream>>>(chunkTot, chunkOff, nChunks);
  k_scanC<<<nChunks, 256, 0, stream>>>(cnt, chunkOff, offs, dinv, N);
  k_bfill<<<nbuck, 256, 0, stream>>>(gcur, bdata, offs, csr, N);
  k_wcvt<<<48, 256, 0, stream>>>(W0, Whid, wt);
  k_xcvt<<<2048, 256, 0, stream>>>(x, xh, N * NF / 4);

  const int gemmGrid = (N + 63) / 64;
  const int aggGrid = (N + 7) / 8;          // 8 nodes (half-waves) per 256-thr block

  // layer 0: xh -> tmp -> h
  k_gemm<<<gemmGrid, 256, 0, stream>>>(xh, wt, dinv, tmp, N);
  k_agg<<<aggGrid, 256, 0, stream>>>(tmp, offs, cnt, csr, dinv, b0, h, N);
  // layer 1
  k_gemm<<<gemmGrid, 256, 0, stream>>>(h, wt + 16384, dinv, tmp, N);
  k_agg<<<aggGrid, 256, 0, stream>>>(tmp, offs, cnt, csr, dinv, bhid, h, N);
  // layer 2
  k_gemm<<<gemmGrid, 256, 0, stream>>>(h, wt + 2 * 16384, dinv, tmp, N);
  k_agg<<<aggGrid, 256, 0, stream>>>(tmp, offs, cnt, csr, dinv, bhid + NF, h, N);

  // pooling + head
  k_pool<<<G, 512, 0, stream>>>(h, batch, Wout, bout, out, N);
}